// Round 2
// baseline (6684.749 us; speedup 1.0000x reference)
//
#include <hip/hip_runtime.h>
#include <hip/hip_bf16.h>

// Problem constants
#define B_    16
#define T_    1000
#define FEAT  771
#define FEATP 776      // 771 padded to multiple of 8 (16B-aligned fp16 rows)
#define H_    512
#define H3    1536
#define KN_   9
#define KHID  4608     // H*KN
#define M_    16000    // B*T
#define NOUT  257      // output column slice [257:514)

typedef _Float16 half8 __attribute__((ext_vector_type(8)));
typedef float    floatx4 __attribute__((ext_vector_type(4)));

__device__ inline half8 h8zero() {
    half8 v;
    #pragma unroll
    for (int i = 0; i < 8; ++i) v[i] = (_Float16)0.f;
    return v;
}

// tanh(z) = 1 - 2/(1+e^{2z})  — saturates correctly at +/-inf, no NaN
__device__ inline float tanh_fast(float z) {
    return 1.0f - 2.0f / (1.0f + __expf(2.0f * z));
}
__device__ inline float sigmoid_fast(float z) {
    return 1.0f / (1.0f + __expf(-z));
}

// ---------------------------------------------------------------------------
// fp32 -> fp16 convert of inputs, padding rows 771 -> 776 with zeros
__global__ void convert_inputs(const float* __restrict__ in, _Float16* __restrict__ A1) {
    size_t i = (size_t)blockIdx.x * 256 + threadIdx.x;
    if (i >= (size_t)M_ * FEATP) return;
    size_t r = i / FEATP;
    int   cc = (int)(i % FEATP);
    A1[i] = (cc < FEAT) ? (_Float16)in[r * FEAT + cc] : (_Float16)0.f;
}

// ---------------------------------------------------------------------------
// LDS-tiled transpose+convert: Wt[n*Kp + k] = (k<K) ? W[k*ldw + coloff + n] : 0
__global__ __launch_bounds__(256) void transpose_w(
    const float* __restrict__ W, _Float16* __restrict__ Wt,
    int K, int N, int ldw, int coloff, int Kp)
{
    __shared__ float tile[32][33];
    const int kb = blockIdx.x * 32;
    const int nb = blockIdx.y * 32;
    const int tx = threadIdx.x & 31;
    const int ty = threadIdx.x >> 5;   // 0..7
    #pragma unroll
    for (int r = ty; r < 32; r += 8) {
        const int k = kb + r, n = nb + tx;
        tile[r][tx] = (k < K && n < N) ? W[(size_t)k * ldw + coloff + n] : 0.f;
    }
    __syncthreads();
    #pragma unroll
    for (int r = ty; r < 32; r += 8) {
        const int n = nb + r, k = kb + tx;
        if (n < N && k < Kp) Wt[(size_t)n * Kp + k] = (_Float16)tile[tx][r];
    }
}

// ---------------------------------------------------------------------------
// Tiled fp16 MFMA GEMM: C[M x N] = A[M x Kp] * Bt[N x Kp]^T, fp32 accumulate.
// 128x128 block tile, BK=32, 4 waves (2x2), each wave 4x4 of 16x16x32 MFMA.
// EPI: 0 = tanh(+bias) -> fp16 ; 1 = raw -> fp16 ; 2 = sigmoid(+bias)*aux -> fp32 out
template <int EPI>
__global__ __launch_bounds__(256) void gemm_kernel(
    const _Float16* __restrict__ A, const _Float16* __restrict__ Bt,
    int Kp, int nk, int Nb,
    _Float16* __restrict__ Ch, float* __restrict__ Cf, int ldc,
    const float* __restrict__ bias, const float* __restrict__ aux)
{
    __shared__ __align__(16) _Float16 As[128][40];  // +8 pad, 16B-aligned rows
    __shared__ __align__(16) _Float16 Bs[128][40];

    const int tid  = threadIdx.x;
    const int m0   = blockIdx.x * 128;
    const int n0   = blockIdx.y * 128;
    const int wave = tid >> 6;
    const int lane = tid & 63;
    const int wr   = (wave >> 1) << 6;   // wave row offset (0/64)
    const int wc   = (wave & 1) << 6;    // wave col offset (0/64)
    const int lrow = lane & 15;
    const int lq   = lane >> 4;          // 0..3
    const int srow = tid >> 1;           // staging row 0..127
    const int scol = (tid & 1) << 4;     // staging col 0 or 16

    floatx4 acc[4][4];
    #pragma unroll
    for (int i = 0; i < 4; ++i)
        #pragma unroll
        for (int j = 0; j < 4; ++j)
            #pragma unroll
            for (int r = 0; r < 4; ++r) acc[i][j][r] = 0.f;

    const _Float16* aRow = A + (size_t)(m0 + srow) * Kp;
    const int  brow   = n0 + srow;
    const _Float16* bRow = Bt + (size_t)brow * Kp;
    const bool bvalid = (brow < Nb);

    for (int kc = 0; kc < nk; ++kc) {
        const int k0 = kc << 5;
        __syncthreads();
        #pragma unroll
        for (int s = 0; s < 2; ++s) {
            const int kk = k0 + scol + s * 8;
            half8 va = h8zero(), vb = h8zero();
            const bool kin = (kk + 8 <= Kp);
            if (kin)           va = *(const half8*)(aRow + kk);
            if (kin && bvalid) vb = *(const half8*)(bRow + kk);
            *(half8*)(&As[srow][scol + s * 8]) = va;
            *(half8*)(&Bs[srow][scol + s * 8]) = vb;
        }
        __syncthreads();

        half8 af[4], bfr[4];
        #pragma unroll
        for (int i = 0; i < 4; ++i) af[i]  = *(const half8*)(&As[wr + i * 16 + lrow][lq * 8]);
        #pragma unroll
        for (int j = 0; j < 4; ++j) bfr[j] = *(const half8*)(&Bs[wc + j * 16 + lrow][lq * 8]);
        #pragma unroll
        for (int i = 0; i < 4; ++i)
            #pragma unroll
            for (int j = 0; j < 4; ++j)
                acc[i][j] = __builtin_amdgcn_mfma_f32_16x16x32_f16(af[i], bfr[j], acc[i][j], 0, 0, 0);
    }

    // Epilogue: C/D layout col=lane&15, row=quad*4+reg
    #pragma unroll
    for (int j = 0; j < 4; ++j) {
        const int col = n0 + wc + j * 16 + lrow;
        if (col >= Nb) continue;
        #pragma unroll
        for (int i = 0; i < 4; ++i) {
            #pragma unroll
            for (int r = 0; r < 4; ++r) {
                const int row = m0 + wr + i * 16 + lq * 4 + r;
                float v = acc[i][j][r];
                if constexpr (EPI == 0) {
                    float z = v + bias[col];
                    Ch[(size_t)row * ldc + col] = (_Float16)tanh_fast(z);
                } else if constexpr (EPI == 1) {
                    Ch[(size_t)row * ldc + col] = (_Float16)v;
                } else {
                    float z = v + bias[col];
                    Cf[(size_t)row * NOUT + col] = sigmoid_fast(z) * aux[(size_t)row * FEAT + 257 + col];
                }
            }
        }
    }
}

// ---------------------------------------------------------------------------
// SRU scan: 8192 chains (b,h), sequential over t. Gates use OLD c (reference).
// Next timestep's operands are prefetched before the current step's sigmoid
// chain so the global-load latency overlaps the dependent ALU chain.
__global__ __launch_bounds__(64) void sru_scan(
    const _Float16* __restrict__ U, const _Float16* __restrict__ Xin,
    _Float16* __restrict__ Xout, const float* __restrict__ v, const float* __restrict__ bg)
{
    const int gid = blockIdx.x * 64 + threadIdx.x;
    const int b = gid >> 9;
    const int h = gid & 511;
    const float vf = v[h],      vr = v[512 + h];
    const float bf = bg[h],     br = bg[512 + h];
    float c = 0.f;
    const _Float16* Ub = U   + (size_t)b * T_ * H3 + h;
    const _Float16* Xb = Xin + (size_t)b * T_ * H_ + h;
    _Float16*       Ob = Xout + (size_t)b * T_ * H_ + h;

    float xt = (float)Ub[0];
    float fp = (float)Ub[512];
    float rp = (float)Ub[1024];
    float x  = (float)Xb[0];
    for (int t = 0; t < T_; ++t) {
        const _Float16* Un = Ub + H3;
        const _Float16* Xn = Xb + H_;
        float nxt = 0.f, nfp = 0.f, nrp = 0.f, nx = 0.f;
        if (t + 1 < T_) {
            nxt = (float)Un[0];
            nfp = (float)Un[512];
            nrp = (float)Un[1024];
            nx  = (float)Xn[0];
        }
        const float f  = sigmoid_fast(fp + vf * c + bf);
        const float r  = sigmoid_fast(rp + vr * c + br);
        const float cn = f * c + (1.0f - f) * xt;
        const float hO = r * cn + (1.0f - r) * x;
        *Ob = (_Float16)hO;
        c = cn;
        xt = nxt; fp = nfp; rp = nrp; x = nx;
        Ub = Un; Xb = Xn; Ob += H_;
    }
}

// ---------------------------------------------------------------------------
// Fused conv6x6(asym pad 3,2) + bias + tanh + maxpool3x3(pad 1).
// Register-blocked conv: each thread computes 4 adjacent ph x all 9 kernels
// (36 fp32 accumulators). Inputs read as dense float4 (16B-aligned); weights
// read as wave-broadcast float4 from a [tap][12] repack. Writes the pooled
// result directly in (b*T+t, h*9+k) fp16 layout for the final GEMM.
__global__ __launch_bounds__(320) void conv_pool(
    const _Float16* __restrict__ X, const float* __restrict__ ck,
    const float* __restrict__ cb, _Float16* __restrict__ A3)
{
    __shared__ __align__(16) float in_s[23][76];    // rows t0-4..t0+18, cols h0-4..h0+71
    __shared__ __align__(16) float cv[9][18][68];   // tanh(conv); -1e30 = outside image
    __shared__ __align__(16) float w_s[36 * 12];    // [tap][12] (9 used) for aligned bcast
    __shared__ float cb_s[9];
    const int tid = threadIdx.x;
    int bi = blockIdx.x;
    const int th = bi & 7;  bi >>= 3;
    const int tt = bi % 63;
    const int b  = bi / 63;
    const int t0 = tt * 16, h0 = th * 64;

    // weights repack: w_s[(ii*6+jj)*12 + k] = ck[k*36 + ii*6 + jj]
    for (int i = tid; i < 324; i += 320) {
        const int k = i / 36, t = i % 36;
        w_s[t * 12 + k] = ck[i];
    }
    if (tid < 9) cb_s[tid] = cb[tid];

    for (int i = tid; i < 23 * 76; i += 320) {
        const int r = i / 76, cc = i % 76;
        const int gt = t0 - 4 + r, gh = h0 - 4 + cc;
        float val = 0.f;   // conv zero-padding
        if (gt >= 0 && gt < T_ && gh >= 0 && gh < H_)
            val = (float)X[((size_t)b * T_ + gt) * H_ + gh];
        in_s[r][cc] = val;
    }
    __syncthreads();

    // conv phase: 18 pt x 17 ph-groups = 306 tasks, one per thread
    if (tid < 306) {
        const int pt  = tid / 17;       // conv row: ct = t0 - 1 + pt
        const int phg = tid % 17;
        const int co  = phg * 4;        // conv col offset: ch = h0 - 1 + co + q
        float acc[4][9];
        #pragma unroll
        for (int q = 0; q < 4; ++q)
            #pragma unroll
            for (int k = 0; k < 9; ++k) acc[q][k] = 0.f;

        #pragma unroll
        for (int ii = 0; ii < 6; ++ii) {
            const float* row = &in_s[pt + ii][co];
            const float4 ra = *(const float4*)(row);
            const float4 rb = *(const float4*)(row + 4);
            const float  r8 = row[8];
            float rr[9] = {ra.x, ra.y, ra.z, ra.w, rb.x, rb.y, rb.z, rb.w, r8};
            #pragma unroll
            for (int jj = 0; jj < 6; ++jj) {
                const float* wp = &w_s[(ii * 6 + jj) * 12];
                const float4 wa = *(const float4*)(wp);
                const float4 wb = *(const float4*)(wp + 4);
                const float  w8 = wp[8];
                const float ww[9] = {wa.x, wa.y, wa.z, wa.w, wb.x, wb.y, wb.z, wb.w, w8};
                #pragma unroll
                for (int k = 0; k < 9; ++k)
                    #pragma unroll
                    for (int q = 0; q < 4; ++q)
                        acc[q][k] = fmaf(ww[k], rr[q + jj], acc[q][k]);
            }
        }

        const int ct = t0 - 1 + pt;
        const bool rok = (ct >= 0) && (ct < T_);
        #pragma unroll
        for (int k = 0; k < 9; ++k) {
            float4 outv;
            float* ov = (float*)&outv;
            #pragma unroll
            for (int q = 0; q < 4; ++q) {
                const int ch = h0 - 1 + co + q;
                const bool ok = rok && (ch >= 0) && (ch < H_);
                ov[q] = ok ? tanh_fast(acc[q][k] + cb_s[k]) : -1e30f;
            }
            *(float4*)(&cv[k][pt][co]) = outv;
        }
    }
    __syncthreads();

    // pool phase: 16 t x 64 h outputs
    for (int i = tid; i < 16 * 64; i += 320) {
        const int pt = i >> 6, ph = i & 63;
        const int gt = t0 + pt;
        if (gt >= T_) continue;
        const int gh = h0 + ph;
        _Float16* dst = A3 + ((size_t)b * T_ + gt) * KHID + gh * KN_;
        #pragma unroll
        for (int k = 0; k < 9; ++k) {
            float m = cv[k][pt][ph];
            m = fmaxf(m, cv[k][pt][ph + 1]);
            m = fmaxf(m, cv[k][pt][ph + 2]);
            m = fmaxf(m, cv[k][pt + 1][ph]);
            m = fmaxf(m, cv[k][pt + 1][ph + 1]);
            m = fmaxf(m, cv[k][pt + 1][ph + 2]);
            m = fmaxf(m, cv[k][pt + 2][ph]);
            m = fmaxf(m, cv[k][pt + 2][ph + 1]);
            m = fmaxf(m, cv[k][pt + 2][ph + 2]);
            dst[k] = (_Float16)m;
        }
    }
}

// ---------------------------------------------------------------------------
extern "C" void kernel_launch(void* const* d_in, const int* in_sizes, int n_in,
                              void* d_out, int out_size, void* d_ws, size_t ws_size,
                              hipStream_t stream) {
    const float* inputs = (const float*)d_in[0];
    const float* W_in   = (const float*)d_in[1];
    const float* b_in   = (const float*)d_in[2];
    const float* W_rnn  = (const float*)d_in[3];
    const float* v_rnn  = (const float*)d_in[4];
    const float* b_rnn  = (const float*)d_in[5];
    const float* conv_k = (const float*)d_in[6];
    const float* conv_b = (const float*)d_in[7];
    const float* W_out  = (const float*)d_in[8];
    const float* b_out  = (const float*)d_in[9];
    float* out = (float*)d_out;

    char* ws = (char*)d_ws;
    size_t off = 0;
    auto take = [&](size_t bytes) -> char* {
        off = (off + 255) & ~(size_t)255;
        char* p = ws + off;
        off += bytes;
        return p;
    };
    _Float16* A1   = (_Float16*)take((size_t)M_ * FEATP * 2);   // inputs fp16, padded
    _Float16* W1T  = (_Float16*)take((size_t)H_ * FEATP * 2);   // W_in^T
    _Float16* W2T0 = (_Float16*)take((size_t)H3 * H_ * 2);      // W_rnn[0]^T
    _Float16* W2T1 = (_Float16*)take((size_t)H3 * H_ * 2);      // W_rnn[1]^T
    _Float16* W3T  = (_Float16*)take((size_t)NOUT * KHID * 2);  // W_out[:,257:514]^T
    _Float16* X0   = (_Float16*)take((size_t)M_ * H_ * 2);
    _Float16* X1   = (_Float16*)take((size_t)M_ * H_ * 2);
    _Float16* U    = (_Float16*)take((size_t)M_ * H3 * 2);
    _Float16* A3   = (_Float16*)take((size_t)M_ * KHID * 2);    // pooled conv, (h*9+k) layout
    _Float16* X2   = X0;  // X0 dead after scan layer 0 -> reuse

    // --- weight/input preprocessing (fp32 -> fp16, transpose to NxK) ---
    {
        size_t n = (size_t)M_ * FEATP;
        convert_inputs<<<dim3((unsigned)((n + 255) / 256)), 256, 0, stream>>>(inputs, A1);
    }
    transpose_w<<<dim3(25, 16), 256, 0, stream>>>(W_in, W1T, FEAT, H_, H_, 0, FEATP);
    transpose_w<<<dim3(16, 48), 256, 0, stream>>>(W_rnn, W2T0, H_, H3, H3, 0, H_);
    transpose_w<<<dim3(16, 48), 256, 0, stream>>>(W_rnn + (size_t)H_ * H3, W2T1, H_, H3, H3, 0, H_);
    transpose_w<<<dim3(144, 9), 256, 0, stream>>>(W_out, W3T, KHID, NOUT, FEAT, 257, KHID);

    // --- G1: X0 = tanh(inputs @ W_in + b_in) ---
    gemm_kernel<0><<<dim3(125, 4), 256, 0, stream>>>(A1, W1T, FEATP, 25, H_, X0, nullptr, H_, b_in, nullptr);

    // --- SRU layer 0 ---
    gemm_kernel<1><<<dim3(125, 12), 256, 0, stream>>>(X0, W2T0, H_, 16, H3, U, nullptr, H3, nullptr, nullptr);
    sru_scan<<<dim3(128), 64, 0, stream>>>(U, X0, X1, v_rnn, b_rnn);

    // --- SRU layer 1 ---
    gemm_kernel<1><<<dim3(125, 12), 256, 0, stream>>>(X1, W2T1, H_, 16, H3, U, nullptr, H3, nullptr, nullptr);
    sru_scan<<<dim3(128), 64, 0, stream>>>(U, X1, X2, v_rnn + 1024, b_rnn + 1024);

    // --- conv + tanh + maxpool fused, producing final-GEMM A matrix ---
    conv_pool<<<dim3(16 * 63 * 8), 320, 0, stream>>>(X2, conv_k, conv_b, A3);

    // --- G3: out = sigmoid(A3 @ W_out[:,257:514] + b_out[257:514]) * inputs[:,:,257:514] ---
    gemm_kernel<2><<<dim3(125, 3), 256, 0, stream>>>(A3, W3T, KHID, 144, NOUT, nullptr, out, NOUT, b_out + 257, inputs);
}

// Round 3
// 3256.565 us; speedup vs baseline: 2.0527x; 2.0527x over previous
//
#include <hip/hip_runtime.h>
#include <hip/hip_bf16.h>

// Problem constants
#define B_    16
#define T_    1000
#define FEAT  771
#define FEATP 776      // 771 padded to multiple of 8 (16B-aligned fp16 rows)
#define H_    512
#define H3    1536
#define KN_   9
#define KHID  4608     // H*KN
#define M_    16000    // B*T
#define NOUT  257      // output column slice [257:514)

typedef _Float16 half8 __attribute__((ext_vector_type(8)));
typedef float    floatx4 __attribute__((ext_vector_type(4)));

__device__ inline half8 h8zero() {
    half8 v;
    #pragma unroll
    for (int i = 0; i < 8; ++i) v[i] = (_Float16)0.f;
    return v;
}

// tanh(z) = 1 - 2/(1+e^{2z})  — saturates correctly at +/-inf, no NaN
__device__ inline float tanh_fast(float z) {
    return 1.0f - 2.0f / (1.0f + __expf(2.0f * z));
}
__device__ inline float sigmoid_fast(float z) {
    return 1.0f / (1.0f + __expf(-z));
}

// ---------------------------------------------------------------------------
// fp32 -> fp16 convert of inputs, padding rows 771 -> 776 with zeros
__global__ void convert_inputs(const float* __restrict__ in, _Float16* __restrict__ A1) {
    size_t i = (size_t)blockIdx.x * 256 + threadIdx.x;
    if (i >= (size_t)M_ * FEATP) return;
    size_t r = i / FEATP;
    int   cc = (int)(i % FEATP);
    A1[i] = (cc < FEAT) ? (_Float16)in[r * FEAT + cc] : (_Float16)0.f;
}

// ---------------------------------------------------------------------------
// LDS-tiled transpose+convert: Wt[n*Kp + k] = (k<K) ? W[k*ldw + coloff + n] : 0
__global__ __launch_bounds__(256) void transpose_w(
    const float* __restrict__ W, _Float16* __restrict__ Wt,
    int K, int N, int ldw, int coloff, int Kp)
{
    __shared__ float tile[32][33];
    const int kb = blockIdx.x * 32;
    const int nb = blockIdx.y * 32;
    const int tx = threadIdx.x & 31;
    const int ty = threadIdx.x >> 5;   // 0..7
    #pragma unroll
    for (int r = ty; r < 32; r += 8) {
        const int k = kb + r, n = nb + tx;
        tile[r][tx] = (k < K && n < N) ? W[(size_t)k * ldw + coloff + n] : 0.f;
    }
    __syncthreads();
    #pragma unroll
    for (int r = ty; r < 32; r += 8) {
        const int n = nb + r, k = kb + tx;
        if (n < N && k < Kp) Wt[(size_t)n * Kp + k] = (_Float16)tile[tx][r];
    }
}

// ---------------------------------------------------------------------------
// Tiled fp16 MFMA GEMM: C[M x N] = A[M x Kp] * Bt[N x Kp]^T, fp32 accumulate.
// 128x128 block tile, BK=32, 4 waves (2x2), each wave 4x4 of 16x16x32 MFMA.
// EPI: 0 = tanh(+bias) -> fp16 ; 1 = raw -> fp16 ; 2 = sigmoid(+bias)*aux -> fp32 out
template <int EPI>
__global__ __launch_bounds__(256) void gemm_kernel(
    const _Float16* __restrict__ A, const _Float16* __restrict__ Bt,
    int Kp, int nk, int Nb,
    _Float16* __restrict__ Ch, float* __restrict__ Cf, int ldc,
    const float* __restrict__ bias, const float* __restrict__ aux)
{
    __shared__ __align__(16) _Float16 As[128][40];  // +8 pad, 16B-aligned rows
    __shared__ __align__(16) _Float16 Bs[128][40];

    const int tid  = threadIdx.x;
    const int m0   = blockIdx.x * 128;
    const int n0   = blockIdx.y * 128;
    const int wave = tid >> 6;
    const int lane = tid & 63;
    const int wr   = (wave >> 1) << 6;   // wave row offset (0/64)
    const int wc   = (wave & 1) << 6;    // wave col offset (0/64)
    const int lrow = lane & 15;
    const int lq   = lane >> 4;          // 0..3
    const int srow = tid >> 1;           // staging row 0..127
    const int scol = (tid & 1) << 4;     // staging col 0 or 16

    floatx4 acc[4][4];
    #pragma unroll
    for (int i = 0; i < 4; ++i)
        #pragma unroll
        for (int j = 0; j < 4; ++j)
            #pragma unroll
            for (int r = 0; r < 4; ++r) acc[i][j][r] = 0.f;

    const _Float16* aRow = A + (size_t)(m0 + srow) * Kp;
    const int  brow   = n0 + srow;
    const _Float16* bRow = Bt + (size_t)brow * Kp;
    const bool bvalid = (brow < Nb);

    for (int kc = 0; kc < nk; ++kc) {
        const int k0 = kc << 5;
        __syncthreads();
        #pragma unroll
        for (int s = 0; s < 2; ++s) {
            const int kk = k0 + scol + s * 8;
            half8 va = h8zero(), vb = h8zero();
            const bool kin = (kk + 8 <= Kp);
            if (kin)           va = *(const half8*)(aRow + kk);
            if (kin && bvalid) vb = *(const half8*)(bRow + kk);
            *(half8*)(&As[srow][scol + s * 8]) = va;
            *(half8*)(&Bs[srow][scol + s * 8]) = vb;
        }
        __syncthreads();

        half8 af[4], bfr[4];
        #pragma unroll
        for (int i = 0; i < 4; ++i) af[i]  = *(const half8*)(&As[wr + i * 16 + lrow][lq * 8]);
        #pragma unroll
        for (int j = 0; j < 4; ++j) bfr[j] = *(const half8*)(&Bs[wc + j * 16 + lrow][lq * 8]);
        #pragma unroll
        for (int i = 0; i < 4; ++i)
            #pragma unroll
            for (int j = 0; j < 4; ++j)
                acc[i][j] = __builtin_amdgcn_mfma_f32_16x16x32_f16(af[i], bfr[j], acc[i][j], 0, 0, 0);
    }

    // Epilogue: C/D layout col=lane&15, row=quad*4+reg
    #pragma unroll
    for (int j = 0; j < 4; ++j) {
        const int col = n0 + wc + j * 16 + lrow;
        if (col >= Nb) continue;
        #pragma unroll
        for (int i = 0; i < 4; ++i) {
            #pragma unroll
            for (int r = 0; r < 4; ++r) {
                const int row = m0 + wr + i * 16 + lq * 4 + r;
                float v = acc[i][j][r];
                if constexpr (EPI == 0) {
                    float z = v + bias[col];
                    Ch[(size_t)row * ldc + col] = (_Float16)tanh_fast(z);
                } else if constexpr (EPI == 1) {
                    Ch[(size_t)row * ldc + col] = (_Float16)v;
                } else {
                    float z = v + bias[col];
                    Cf[(size_t)row * NOUT + col] = sigmoid_fast(z) * aux[(size_t)row * FEAT + 257 + col];
                }
            }
        }
    }
}

// ---------------------------------------------------------------------------
// SRU scan: 8192 chains (b,h), sequential over t. Gates use OLD c (reference).
// Next timestep's operands are prefetched before the current step's sigmoid
// chain so the global-load latency overlaps the dependent ALU chain.
__global__ __launch_bounds__(64) void sru_scan(
    const _Float16* __restrict__ U, const _Float16* __restrict__ Xin,
    _Float16* __restrict__ Xout, const float* __restrict__ v, const float* __restrict__ bg)
{
    const int gid = blockIdx.x * 64 + threadIdx.x;
    const int b = gid >> 9;
    const int h = gid & 511;
    const float vf = v[h],      vr = v[512 + h];
    const float bf = bg[h],     br = bg[512 + h];
    float c = 0.f;
    const _Float16* Ub = U   + (size_t)b * T_ * H3 + h;
    const _Float16* Xb = Xin + (size_t)b * T_ * H_ + h;
    _Float16*       Ob = Xout + (size_t)b * T_ * H_ + h;

    float xt = (float)Ub[0];
    float fp = (float)Ub[512];
    float rp = (float)Ub[1024];
    float x  = (float)Xb[0];
    for (int t = 0; t < T_; ++t) {
        const _Float16* Un = Ub + H3;
        const _Float16* Xn = Xb + H_;
        float nxt = 0.f, nfp = 0.f, nrp = 0.f, nx = 0.f;
        if (t + 1 < T_) {
            nxt = (float)Un[0];
            nfp = (float)Un[512];
            nrp = (float)Un[1024];
            nx  = (float)Xn[0];
        }
        const float f  = sigmoid_fast(fp + vf * c + bf);
        const float r  = sigmoid_fast(rp + vr * c + br);
        const float cn = f * c + (1.0f - f) * xt;
        const float hO = r * cn + (1.0f - r) * x;
        *Ob = (_Float16)hO;
        c = cn;
        xt = nxt; fp = nfp; rp = nrp; x = nx;
        Ub = Un; Xb = Xn; Ob += H_;
    }
}

// ---------------------------------------------------------------------------
// Fused conv6x6(asym pad 3,2) + bias + tanh + maxpool3x3(pad 1).
// Register-blocked conv with NO local arrays (everything is named vectors /
// compile-time swizzles so nothing can be demoted to scratch).
// Each thread: 4 adjacent ph (vector lanes) x all 9 kernels (9 floatx4 accs).
struct AccK { floatx4 a0, a1, a2, a3, a4, a5, a6, a7, a8; };

template <int JJ>
__device__ inline floatx4 window4(floatx4 a, floatx4 b, float r8) {
    floatx4 w;
    if constexpr (JJ == 0)      { w = a; }
    else if constexpr (JJ == 1) { w[0] = a[1]; w[1] = a[2]; w[2] = a[3]; w[3] = b[0]; }
    else if constexpr (JJ == 2) { w[0] = a[2]; w[1] = a[3]; w[2] = b[0]; w[3] = b[1]; }
    else if constexpr (JJ == 3) { w[0] = a[3]; w[1] = b[0]; w[2] = b[1]; w[3] = b[2]; }
    else if constexpr (JJ == 4) { w = b; }
    else                        { w[0] = b[1]; w[1] = b[2]; w[2] = b[3]; w[3] = r8; }
    return w;
}

__device__ inline void tap_fma(floatx4 win, const float* __restrict__ wp, AccK& A) {
    const floatx4 wA = *(const floatx4*)wp;         // k0..3
    const floatx4 wB = *(const floatx4*)(wp + 4);   // k4..7
    const float   w8 = wp[8];                       // k8
    A.a0 += wA[0] * win;  A.a1 += wA[1] * win;  A.a2 += wA[2] * win;  A.a3 += wA[3] * win;
    A.a4 += wB[0] * win;  A.a5 += wB[1] * win;  A.a6 += wB[2] * win;  A.a7 += wB[3] * win;
    A.a8 += w8 * win;
}

__global__ __launch_bounds__(320) void conv_pool(
    const _Float16* __restrict__ X, const float* __restrict__ ck,
    const float* __restrict__ cb, _Float16* __restrict__ A3)
{
    __shared__ __align__(16) float in_s[23][76];    // rows t0-4..t0+18, cols h0-4..h0+71
    __shared__ __align__(16) float cv[9][18][72];   // tanh(conv); -1e30 = outside image
    __shared__ __align__(16) float w_s[36 * 12];    // [tap][12] (9 used), 16B-aligned taps
    __shared__ float cb_s[9];
    const int tid = threadIdx.x;
    int bi = blockIdx.x;
    const int th = bi & 7;  bi >>= 3;
    const int tt = bi % 63;
    const int b  = bi / 63;
    const int t0 = tt * 16, h0 = th * 64;

    // weights repack: w_s[(ii*6+jj)*12 + k] = ck[k*36 + ii*6 + jj]
    for (int i = tid; i < 324; i += 320) {
        const int k = i / 36, t = i % 36;
        w_s[t * 12 + k] = ck[i];
    }
    if (tid < 9) cb_s[tid] = cb[tid];

    for (int i = tid; i < 23 * 76; i += 320) {
        const int r = i / 76, cc = i % 76;
        const int gt = t0 - 4 + r, gh = h0 - 4 + cc;
        float val = 0.f;   // conv zero-padding
        if (gt >= 0 && gt < T_ && gh >= 0 && gh < H_)
            val = (float)X[((size_t)b * T_ + gt) * H_ + gh];
        in_s[r][cc] = val;
    }
    __syncthreads();

    // conv phase: 18 pt x 17 ph-groups = 306 tasks, one per thread
    if (tid < 306) {
        const int pt = tid / 17;        // conv row: ct = t0 - 1 + pt
        const int co = (tid % 17) * 4;  // conv col offset: ch = h0 - 1 + co + q
        AccK A;
        A.a0 = 0.f; A.a1 = 0.f; A.a2 = 0.f; A.a3 = 0.f; A.a4 = 0.f;
        A.a5 = 0.f; A.a6 = 0.f; A.a7 = 0.f; A.a8 = 0.f;

        #pragma unroll
        for (int ii = 0; ii < 6; ++ii) {
            const float* row = &in_s[pt + ii][co];
            const floatx4 ra = *(const floatx4*)(row);
            const floatx4 rb = *(const floatx4*)(row + 4);
            const float   r8 = row[8];
            const float* wb = &w_s[(ii * 6) * 12];
            tap_fma(window4<0>(ra, rb, r8), wb,          A);
            tap_fma(window4<1>(ra, rb, r8), wb + 1 * 12, A);
            tap_fma(window4<2>(ra, rb, r8), wb + 2 * 12, A);
            tap_fma(window4<3>(ra, rb, r8), wb + 3 * 12, A);
            tap_fma(window4<4>(ra, rb, r8), wb + 4 * 12, A);
            tap_fma(window4<5>(ra, rb, r8), wb + 5 * 12, A);
        }

        const int ct = t0 - 1 + pt;
        const bool rok = (ct >= 0) && (ct < T_);
        const int chb = h0 - 1 + co;
        const bool ok0 = rok && (chb + 0 >= 0) && (chb + 0 < H_);
        const bool ok1 = rok && (chb + 1 >= 0) && (chb + 1 < H_);
        const bool ok2 = rok && (chb + 2 >= 0) && (chb + 2 < H_);
        const bool ok3 = rok && (chb + 3 >= 0) && (chb + 3 < H_);
        #define EMIT_K(K, MEM)                                                   \
        {                                                                        \
            const floatx4 v = A.MEM;                                             \
            floatx4 o;                                                           \
            o[0] = ok0 ? tanh_fast(v[0] + cb_s[K]) : -1e30f;                     \
            o[1] = ok1 ? tanh_fast(v[1] + cb_s[K]) : -1e30f;                     \
            o[2] = ok2 ? tanh_fast(v[2] + cb_s[K]) : -1e30f;                     \
            o[3] = ok3 ? tanh_fast(v[3] + cb_s[K]) : -1e30f;                     \
            *(floatx4*)(&cv[K][pt][co]) = o;                                     \
        }
        EMIT_K(0, a0) EMIT_K(1, a1) EMIT_K(2, a2) EMIT_K(3, a3) EMIT_K(4, a4)
        EMIT_K(5, a5) EMIT_K(6, a6) EMIT_K(7, a7) EMIT_K(8, a8)
        #undef EMIT_K
    }
    __syncthreads();

    // pool phase: 16 t x 64 h outputs
    for (int i = tid; i < 16 * 64; i += 320) {
        const int pt = i >> 6, ph = i & 63;
        const int gt = t0 + pt;
        if (gt >= T_) continue;
        const int gh = h0 + ph;
        _Float16* dst = A3 + ((size_t)b * T_ + gt) * KHID + gh * KN_;
        #pragma unroll
        for (int k = 0; k < 9; ++k) {
            float m = cv[k][pt][ph];
            m = fmaxf(m, cv[k][pt][ph + 1]);
            m = fmaxf(m, cv[k][pt][ph + 2]);
            m = fmaxf(m, cv[k][pt + 1][ph]);
            m = fmaxf(m, cv[k][pt + 1][ph + 1]);
            m = fmaxf(m, cv[k][pt + 1][ph + 2]);
            m = fmaxf(m, cv[k][pt + 2][ph]);
            m = fmaxf(m, cv[k][pt + 2][ph + 1]);
            m = fmaxf(m, cv[k][pt + 2][ph + 2]);
            dst[k] = (_Float16)m;
        }
    }
}

// ---------------------------------------------------------------------------
extern "C" void kernel_launch(void* const* d_in, const int* in_sizes, int n_in,
                              void* d_out, int out_size, void* d_ws, size_t ws_size,
                              hipStream_t stream) {
    const float* inputs = (const float*)d_in[0];
    const float* W_in   = (const float*)d_in[1];
    const float* b_in   = (const float*)d_in[2];
    const float* W_rnn  = (const float*)d_in[3];
    const float* v_rnn  = (const float*)d_in[4];
    const float* b_rnn  = (const float*)d_in[5];
    const float* conv_k = (const float*)d_in[6];
    const float* conv_b = (const float*)d_in[7];
    const float* W_out  = (const float*)d_in[8];
    const float* b_out  = (const float*)d_in[9];
    float* out = (float*)d_out;

    char* ws = (char*)d_ws;
    size_t off = 0;
    auto take = [&](size_t bytes) -> char* {
        off = (off + 255) & ~(size_t)255;
        char* p = ws + off;
        off += bytes;
        return p;
    };
    _Float16* A1   = (_Float16*)take((size_t)M_ * FEATP * 2);   // inputs fp16, padded
    _Float16* W1T  = (_Float16*)take((size_t)H_ * FEATP * 2);   // W_in^T
    _Float16* W2T0 = (_Float16*)take((size_t)H3 * H_ * 2);      // W_rnn[0]^T
    _Float16* W2T1 = (_Float16*)take((size_t)H3 * H_ * 2);      // W_rnn[1]^T
    _Float16* W3T  = (_Float16*)take((size_t)NOUT * KHID * 2);  // W_out[:,257:514]^T
    _Float16* X0   = (_Float16*)take((size_t)M_ * H_ * 2);
    _Float16* X1   = (_Float16*)take((size_t)M_ * H_ * 2);
    _Float16* U    = (_Float16*)take((size_t)M_ * H3 * 2);
    _Float16* A3   = (_Float16*)take((size_t)M_ * KHID * 2);    // pooled conv, (h*9+k) layout
    _Float16* X2   = X0;  // X0 dead after scan layer 0 -> reuse

    // --- weight/input preprocessing (fp32 -> fp16, transpose to NxK) ---
    {
        size_t n = (size_t)M_ * FEATP;
        convert_inputs<<<dim3((unsigned)((n + 255) / 256)), 256, 0, stream>>>(inputs, A1);
    }
    transpose_w<<<dim3(25, 16), 256, 0, stream>>>(W_in, W1T, FEAT, H_, H_, 0, FEATP);
    transpose_w<<<dim3(16, 48), 256, 0, stream>>>(W_rnn, W2T0, H_, H3, H3, 0, H_);
    transpose_w<<<dim3(16, 48), 256, 0, stream>>>(W_rnn + (size_t)H_ * H3, W2T1, H_, H3, H3, 0, H_);
    transpose_w<<<dim3(144, 9), 256, 0, stream>>>(W_out, W3T, KHID, NOUT, FEAT, 257, KHID);

    // --- G1: X0 = tanh(inputs @ W_in + b_in) ---
    gemm_kernel<0><<<dim3(125, 4), 256, 0, stream>>>(A1, W1T, FEATP, 25, H_, X0, nullptr, H_, b_in, nullptr);

    // --- SRU layer 0 ---
    gemm_kernel<1><<<dim3(125, 12), 256, 0, stream>>>(X0, W2T0, H_, 16, H3, U, nullptr, H3, nullptr, nullptr);
    sru_scan<<<dim3(128), 64, 0, stream>>>(U, X0, X1, v_rnn, b_rnn);

    // --- SRU layer 1 ---
    gemm_kernel<1><<<dim3(125, 12), 256, 0, stream>>>(X1, W2T1, H_, 16, H3, U, nullptr, H3, nullptr, nullptr);
    sru_scan<<<dim3(128), 64, 0, stream>>>(U, X1, X2, v_rnn + 1024, b_rnn + 1024);

    // --- conv + tanh + maxpool fused, producing final-GEMM A matrix ---
    conv_pool<<<dim3(16 * 63 * 8), 320, 0, stream>>>(X2, conv_k, conv_b, A3);

    // --- G3: out = sigmoid(A3 @ W_out[:,257:514] + b_out[257:514]) * inputs[:,:,257:514] ---
    gemm_kernel<2><<<dim3(125, 3), 256, 0, stream>>>(A3, W3T, KHID, 144, NOUT, nullptr, out, NOUT, b_out + 257, inputs);
}

// Round 4
// 1383.038 us; speedup vs baseline: 4.8334x; 2.3546x over previous
//
#include <hip/hip_runtime.h>
#include <hip/hip_bf16.h>

// Problem constants
#define B_    16
#define T_    1000
#define FEAT  771
#define FEATP 776      // 771 padded to multiple of 8 (16B-aligned fp16 rows)
#define H_    512
#define H3    1536
#define KN_   9
#define KHID  4608     // H*KN
#define M_    16000    // B*T
#define NOUT  257      // output column slice [257:514)

typedef _Float16 half8 __attribute__((ext_vector_type(8)));
typedef float    floatx4 __attribute__((ext_vector_type(4)));

__device__ inline half8 h8zero() {
    half8 v;
    #pragma unroll
    for (int i = 0; i < 8; ++i) v[i] = (_Float16)0.f;
    return v;
}

// tanh(z) = 1 - 2/(1+e^{2z})  — saturates correctly at +/-inf, no NaN
__device__ inline float tanh_fast(float z) {
    return 1.0f - 2.0f / (1.0f + __expf(2.0f * z));
}
__device__ inline float sigmoid_fast(float z) {
    return 1.0f / (1.0f + __expf(-z));
}

// ---------------------------------------------------------------------------
// fp32 -> fp16 convert of inputs, padding rows 771 -> 776 with zeros
__global__ void convert_inputs(const float* __restrict__ in, _Float16* __restrict__ A1) {
    size_t i = (size_t)blockIdx.x * 256 + threadIdx.x;
    if (i >= (size_t)M_ * FEATP) return;
    size_t r = i / FEATP;
    int   cc = (int)(i % FEATP);
    A1[i] = (cc < FEAT) ? (_Float16)in[r * FEAT + cc] : (_Float16)0.f;
}

// ---------------------------------------------------------------------------
// LDS-tiled transpose+convert: Wt[n*Kp + k] = (k<K) ? W[k*ldw + coloff + n] : 0
__global__ __launch_bounds__(256) void transpose_w(
    const float* __restrict__ W, _Float16* __restrict__ Wt,
    int K, int N, int ldw, int coloff, int Kp)
{
    __shared__ float tile[32][33];
    const int kb = blockIdx.x * 32;
    const int nb = blockIdx.y * 32;
    const int tx = threadIdx.x & 31;
    const int ty = threadIdx.x >> 5;   // 0..7
    #pragma unroll
    for (int r = ty; r < 32; r += 8) {
        const int k = kb + r, n = nb + tx;
        tile[r][tx] = (k < K && n < N) ? W[(size_t)k * ldw + coloff + n] : 0.f;
    }
    __syncthreads();
    #pragma unroll
    for (int r = ty; r < 32; r += 8) {
        const int n = nb + r, k = kb + tx;
        if (n < N && k < Kp) Wt[(size_t)n * Kp + k] = (_Float16)tile[tx][r];
    }
}

// ---------------------------------------------------------------------------
// Tiled fp16 MFMA GEMM: C[M x N] = A[M x Kp] * Bt[N x Kp]^T, fp32 accumulate.
// 128x128 block tile, BK=32, 4 waves (2x2), each wave 4x4 of 16x16x32 MFMA.
// EPI: 0 = tanh(+bias) -> fp16 ; 1 = raw -> fp16 ; 2 = sigmoid(+bias)*aux -> fp32 out
template <int EPI>
__global__ __launch_bounds__(256) void gemm_kernel(
    const _Float16* __restrict__ A, const _Float16* __restrict__ Bt,
    int Kp, int nk, int Nb,
    _Float16* __restrict__ Ch, float* __restrict__ Cf, int ldc,
    const float* __restrict__ bias, const float* __restrict__ aux)
{
    __shared__ __align__(16) _Float16 As[128][40];  // +8 pad, 16B-aligned rows
    __shared__ __align__(16) _Float16 Bs[128][40];

    const int tid  = threadIdx.x;
    const int m0   = blockIdx.x * 128;
    const int n0   = blockIdx.y * 128;
    const int wave = tid >> 6;
    const int lane = tid & 63;
    const int wr   = (wave >> 1) << 6;   // wave row offset (0/64)
    const int wc   = (wave & 1) << 6;    // wave col offset (0/64)
    const int lrow = lane & 15;
    const int lq   = lane >> 4;          // 0..3
    const int srow = tid >> 1;           // staging row 0..127
    const int scol = (tid & 1) << 4;     // staging col 0 or 16

    floatx4 acc[4][4];
    #pragma unroll
    for (int i = 0; i < 4; ++i)
        #pragma unroll
        for (int j = 0; j < 4; ++j)
            #pragma unroll
            for (int r = 0; r < 4; ++r) acc[i][j][r] = 0.f;

    const _Float16* aRow = A + (size_t)(m0 + srow) * Kp;
    const int  brow   = n0 + srow;
    const _Float16* bRow = Bt + (size_t)brow * Kp;
    const bool bvalid = (brow < Nb);

    for (int kc = 0; kc < nk; ++kc) {
        const int k0 = kc << 5;
        __syncthreads();
        #pragma unroll
        for (int s = 0; s < 2; ++s) {
            const int kk = k0 + scol + s * 8;
            half8 va = h8zero(), vb = h8zero();
            const bool kin = (kk + 8 <= Kp);
            if (kin)           va = *(const half8*)(aRow + kk);
            if (kin && bvalid) vb = *(const half8*)(bRow + kk);
            *(half8*)(&As[srow][scol + s * 8]) = va;
            *(half8*)(&Bs[srow][scol + s * 8]) = vb;
        }
        __syncthreads();

        half8 af[4], bfr[4];
        #pragma unroll
        for (int i = 0; i < 4; ++i) af[i]  = *(const half8*)(&As[wr + i * 16 + lrow][lq * 8]);
        #pragma unroll
        for (int j = 0; j < 4; ++j) bfr[j] = *(const half8*)(&Bs[wc + j * 16 + lrow][lq * 8]);
        #pragma unroll
        for (int i = 0; i < 4; ++i)
            #pragma unroll
            for (int j = 0; j < 4; ++j)
                acc[i][j] = __builtin_amdgcn_mfma_f32_16x16x32_f16(af[i], bfr[j], acc[i][j], 0, 0, 0);
    }

    // Epilogue: C/D layout col=lane&15, row=quad*4+reg
    #pragma unroll
    for (int j = 0; j < 4; ++j) {
        const int col = n0 + wc + j * 16 + lrow;
        if (col >= Nb) continue;
        #pragma unroll
        for (int i = 0; i < 4; ++i) {
            #pragma unroll
            for (int r = 0; r < 4; ++r) {
                const int row = m0 + wr + i * 16 + lq * 4 + r;
                float v = acc[i][j][r];
                if constexpr (EPI == 0) {
                    float z = v + bias[col];
                    Ch[(size_t)row * ldc + col] = (_Float16)tanh_fast(z);
                } else if constexpr (EPI == 1) {
                    Ch[(size_t)row * ldc + col] = (_Float16)v;
                } else {
                    float z = v + bias[col];
                    Cf[(size_t)row * NOUT + col] = sigmoid_fast(z) * aux[(size_t)row * FEAT + 257 + col];
                }
            }
        }
    }
}

// ---------------------------------------------------------------------------
// SRU scan: 8192 chains (b,h), sequential over t. Gates use OLD c (reference).
// Next timestep's operands are prefetched before the current step's sigmoid
// chain so the global-load latency overlaps the dependent ALU chain.
__global__ __launch_bounds__(64) void sru_scan(
    const _Float16* __restrict__ U, const _Float16* __restrict__ Xin,
    _Float16* __restrict__ Xout, const float* __restrict__ v, const float* __restrict__ bg)
{
    const int gid = blockIdx.x * 64 + threadIdx.x;
    const int b = gid >> 9;
    const int h = gid & 511;
    const float vf = v[h],      vr = v[512 + h];
    const float bf = bg[h],     br = bg[512 + h];
    float c = 0.f;
    const _Float16* Ub = U   + (size_t)b * T_ * H3 + h;
    const _Float16* Xb = Xin + (size_t)b * T_ * H_ + h;
    _Float16*       Ob = Xout + (size_t)b * T_ * H_ + h;

    float xt = (float)Ub[0];
    float fp = (float)Ub[512];
    float rp = (float)Ub[1024];
    float x  = (float)Xb[0];
    for (int t = 0; t < T_; ++t) {
        const _Float16* Un = Ub + H3;
        const _Float16* Xn = Xb + H_;
        float nxt = 0.f, nfp = 0.f, nrp = 0.f, nx = 0.f;
        if (t + 1 < T_) {
            nxt = (float)Un[0];
            nfp = (float)Un[512];
            nrp = (float)Un[1024];
            nx  = (float)Xn[0];
        }
        const float f  = sigmoid_fast(fp + vf * c + bf);
        const float r  = sigmoid_fast(rp + vr * c + br);
        const float cn = f * c + (1.0f - f) * xt;
        const float hO = r * cn + (1.0f - r) * x;
        *Ob = (_Float16)hO;
        c = cn;
        xt = nxt; fp = nfp; rp = nrp; x = nx;
        Ub = Un; Xb = Xn; Ob += H_;
    }
}

// ---------------------------------------------------------------------------
// Fused conv6x6(asym pad 3,2) + bias + tanh + maxpool3x3(pad 1).
// Register-pressure-bounded conv: two passes over the 6 rows (k0..4, then
// k5..8) so at most 20 accumulator VGPRs persist; row loop kept ROLLED
// (#pragma unroll 1) so only one row's taps are live at a time -> no scratch.
template <int JJ>
__device__ inline floatx4 window4(floatx4 a, floatx4 b, float r8) {
    floatx4 w;
    if constexpr (JJ == 0)      { w = a; }
    else if constexpr (JJ == 1) { w[0] = a[1]; w[1] = a[2]; w[2] = a[3]; w[3] = b[0]; }
    else if constexpr (JJ == 2) { w[0] = a[2]; w[1] = a[3]; w[2] = b[0]; w[3] = b[1]; }
    else if constexpr (JJ == 3) { w[0] = a[3]; w[1] = b[0]; w[2] = b[1]; w[3] = b[2]; }
    else if constexpr (JJ == 4) { w = b; }
    else                        { w[0] = b[1]; w[1] = b[2]; w[2] = b[3]; w[3] = r8; }
    return w;
}

// One pass over 6 rows x 6 taps accumulating NK kernel channels.
// ws: tap-major weights, WS floats per tap (16B-aligned). NK = 5 or 4.
template <int NK, int WS>
__device__ inline void conv_pass(
    const float* __restrict__ inb,   // &in_s[pt][co], row stride 76 floats
    const float* __restrict__ ws,
    floatx4& c0, floatx4& c1, floatx4& c2, floatx4& c3, floatx4& c4)
{
    #pragma unroll 1
    for (int ii = 0; ii < 6; ++ii) {
        const float* row = inb + ii * 76;
        const floatx4 ra = *(const floatx4*)(row);
        const floatx4 rb = *(const floatx4*)(row + 4);
        const float   r8 = row[8];
        const float* wt = ws + (ii * 6) * WS;
        #define TAP(J)                                                         \
        {                                                                      \
            const floatx4 win = window4<J>(ra, rb, r8);                        \
            const float* wp = wt + (J) * WS;                                   \
            const floatx4 wv = *(const floatx4*)wp;                            \
            c0 += wv[0] * win; c1 += wv[1] * win;                              \
            c2 += wv[2] * win; c3 += wv[3] * win;                              \
            if constexpr (NK == 5) { c4 += wp[4] * win; }                      \
        }
        TAP(0) TAP(1) TAP(2) TAP(3) TAP(4) TAP(5)
        #undef TAP
    }
}

__global__ __launch_bounds__(320, 2) void conv_pool(
    const _Float16* __restrict__ X, const float* __restrict__ ck,
    const float* __restrict__ cb, _Float16* __restrict__ A3)
{
    __shared__ __align__(16) float in_s[23][76];    // rows t0-4..t0+18, cols h0-4..h0+71
    __shared__ __align__(16) float cv[9][18][72];   // tanh(conv); -1e30 = outside image
    __shared__ __align__(16) float w0_s[36 * 8];    // [tap][8]: k0..4 in slots 0..4
    __shared__ __align__(16) float w1_s[36 * 4];    // [tap][4]: k5..8
    __shared__ float cb_s[9];
    const int tid = threadIdx.x;
    int bi = blockIdx.x;
    const int th = bi & 7;  bi >>= 3;
    const int tt = bi % 63;
    const int b  = bi / 63;
    const int t0 = tt * 16, h0 = th * 64;

    // weights repack (tap-major): ck[k*36 + t] -> w0_s[t*8+k] (k<5), w1_s[t*4+k-5]
    for (int i = tid; i < 324; i += 320) {
        const int k = i / 36, t = i % 36;
        const float w = ck[i];
        if (k < 5) w0_s[t * 8 + k] = w;
        else       w1_s[t * 4 + (k - 5)] = w;
    }
    if (tid < 9) cb_s[tid] = cb[tid];

    for (int i = tid; i < 23 * 76; i += 320) {
        const int r = i / 76, cc = i % 76;
        const int gt = t0 - 4 + r, gh = h0 - 4 + cc;
        float val = 0.f;   // conv zero-padding
        if (gt >= 0 && gt < T_ && gh >= 0 && gh < H_)
            val = (float)X[((size_t)b * T_ + gt) * H_ + gh];
        in_s[r][cc] = val;
    }
    __syncthreads();

    // conv phase: 18 pt x 17 ph-groups = 306 tasks, one per thread
    if (tid < 306) {
        const int pt = tid / 17;        // conv row: ct = t0 - 1 + pt
        const int co = (tid % 17) * 4;  // conv col offset: ch = h0 - 1 + co + q
        const float* inb = &in_s[pt][co];

        const int ct = t0 - 1 + pt;
        const bool rok = (ct >= 0) && (ct < T_);
        const int chb = h0 - 1 + co;
        const bool ok0 = rok && (chb + 0 >= 0) && (chb + 0 < H_);
        const bool ok1 = rok && (chb + 1 >= 0) && (chb + 1 < H_);
        const bool ok2 = rok && (chb + 2 >= 0) && (chb + 2 < H_);
        const bool ok3 = rok && (chb + 3 >= 0) && (chb + 3 < H_);

        #define EMIT_K(K, VV)                                                  \
        {                                                                      \
            const floatx4 vz = (VV);                                           \
            floatx4 o;                                                         \
            o[0] = ok0 ? tanh_fast(vz[0] + cb_s[K]) : -1e30f;                  \
            o[1] = ok1 ? tanh_fast(vz[1] + cb_s[K]) : -1e30f;                  \
            o[2] = ok2 ? tanh_fast(vz[2] + cb_s[K]) : -1e30f;                  \
            o[3] = ok3 ? tanh_fast(vz[3] + cb_s[K]) : -1e30f;                  \
            *(floatx4*)(&cv[K][pt][co]) = o;                                   \
        }

        {   // pass 0: kernels 0..4
            floatx4 c0 = 0.f, c1 = 0.f, c2 = 0.f, c3 = 0.f, c4 = 0.f;
            conv_pass<5, 8>(inb, w0_s, c0, c1, c2, c3, c4);
            EMIT_K(0, c0) EMIT_K(1, c1) EMIT_K(2, c2) EMIT_K(3, c3) EMIT_K(4, c4)
        }
        {   // pass 1: kernels 5..8
            floatx4 c0 = 0.f, c1 = 0.f, c2 = 0.f, c3 = 0.f, c4 = 0.f;
            conv_pass<4, 4>(inb, w1_s, c0, c1, c2, c3, c4);
            EMIT_K(5, c0) EMIT_K(6, c1) EMIT_K(7, c2) EMIT_K(8, c3)
        }
        #undef EMIT_K
    }
    __syncthreads();

    // pool phase: 16 t x 64 h outputs
    for (int i = tid; i < 16 * 64; i += 320) {
        const int pt = i >> 6, ph = i & 63;
        const int gt = t0 + pt;
        if (gt >= T_) continue;
        const int gh = h0 + ph;
        _Float16* dst = A3 + ((size_t)b * T_ + gt) * KHID + gh * KN_;
        #pragma unroll
        for (int k = 0; k < 9; ++k) {
            float m = cv[k][pt][ph];
            m = fmaxf(m, cv[k][pt][ph + 1]);
            m = fmaxf(m, cv[k][pt][ph + 2]);
            m = fmaxf(m, cv[k][pt + 1][ph]);
            m = fmaxf(m, cv[k][pt + 1][ph + 1]);
            m = fmaxf(m, cv[k][pt + 1][ph + 2]);
            m = fmaxf(m, cv[k][pt + 2][ph]);
            m = fmaxf(m, cv[k][pt + 2][ph + 1]);
            m = fmaxf(m, cv[k][pt + 2][ph + 2]);
            dst[k] = (_Float16)m;
        }
    }
}

// ---------------------------------------------------------------------------
extern "C" void kernel_launch(void* const* d_in, const int* in_sizes, int n_in,
                              void* d_out, int out_size, void* d_ws, size_t ws_size,
                              hipStream_t stream) {
    const float* inputs = (const float*)d_in[0];
    const float* W_in   = (const float*)d_in[1];
    const float* b_in   = (const float*)d_in[2];
    const float* W_rnn  = (const float*)d_in[3];
    const float* v_rnn  = (const float*)d_in[4];
    const float* b_rnn  = (const float*)d_in[5];
    const float* conv_k = (const float*)d_in[6];
    const float* conv_b = (const float*)d_in[7];
    const float* W_out  = (const float*)d_in[8];
    const float* b_out  = (const float*)d_in[9];
    float* out = (float*)d_out;

    char* ws = (char*)d_ws;
    size_t off = 0;
    auto take = [&](size_t bytes) -> char* {
        off = (off + 255) & ~(size_t)255;
        char* p = ws + off;
        off += bytes;
        return p;
    };
    _Float16* A1   = (_Float16*)take((size_t)M_ * FEATP * 2);   // inputs fp16, padded
    _Float16* W1T  = (_Float16*)take((size_t)H_ * FEATP * 2);   // W_in^T
    _Float16* W2T0 = (_Float16*)take((size_t)H3 * H_ * 2);      // W_rnn[0]^T
    _Float16* W2T1 = (_Float16*)take((size_t)H3 * H_ * 2);      // W_rnn[1]^T
    _Float16* W3T  = (_Float16*)take((size_t)NOUT * KHID * 2);  // W_out[:,257:514]^T
    _Float16* X0   = (_Float16*)take((size_t)M_ * H_ * 2);
    _Float16* X1   = (_Float16*)take((size_t)M_ * H_ * 2);
    _Float16* U    = (_Float16*)take((size_t)M_ * H3 * 2);
    _Float16* A3   = (_Float16*)take((size_t)M_ * KHID * 2);    // pooled conv, (h*9+k) layout
    _Float16* X2   = X0;  // X0 dead after scan layer 0 -> reuse

    // --- weight/input preprocessing (fp32 -> fp16, transpose to NxK) ---
    {
        size_t n = (size_t)M_ * FEATP;
        convert_inputs<<<dim3((unsigned)((n + 255) / 256)), 256, 0, stream>>>(inputs, A1);
    }
    transpose_w<<<dim3(25, 16), 256, 0, stream>>>(W_in, W1T, FEAT, H_, H_, 0, FEATP);
    transpose_w<<<dim3(16, 48), 256, 0, stream>>>(W_rnn, W2T0, H_, H3, H3, 0, H_);
    transpose_w<<<dim3(16, 48), 256, 0, stream>>>(W_rnn + (size_t)H_ * H3, W2T1, H_, H3, H3, 0, H_);
    transpose_w<<<dim3(144, 9), 256, 0, stream>>>(W_out, W3T, KHID, NOUT, FEAT, 257, KHID);

    // --- G1: X0 = tanh(inputs @ W_in + b_in) ---
    gemm_kernel<0><<<dim3(125, 4), 256, 0, stream>>>(A1, W1T, FEATP, 25, H_, X0, nullptr, H_, b_in, nullptr);

    // --- SRU layer 0 ---
    gemm_kernel<1><<<dim3(125, 12), 256, 0, stream>>>(X0, W2T0, H_, 16, H3, U, nullptr, H3, nullptr, nullptr);
    sru_scan<<<dim3(128), 64, 0, stream>>>(U, X0, X1, v_rnn, b_rnn);

    // --- SRU layer 1 ---
    gemm_kernel<1><<<dim3(125, 12), 256, 0, stream>>>(X1, W2T1, H_, 16, H3, U, nullptr, H3, nullptr, nullptr);
    sru_scan<<<dim3(128), 64, 0, stream>>>(U, X1, X2, v_rnn + 1024, b_rnn + 1024);

    // --- conv + tanh + maxpool fused, producing final-GEMM A matrix ---
    conv_pool<<<dim3(16 * 63 * 8), 320, 0, stream>>>(X2, conv_k, conv_b, A3);

    // --- G3: out = sigmoid(A3 @ W_out[:,257:514] + b_out[257:514]) * inputs[:,:,257:514] ---
    gemm_kernel<2><<<dim3(125, 3), 256, 0, stream>>>(A3, W3T, KHID, 144, NOUT, nullptr, out, NOUT, b_out + 257, inputs);
}

// Round 5
// 946.584 us; speedup vs baseline: 7.0620x; 1.4611x over previous
//
#include <hip/hip_runtime.h>
#include <hip/hip_bf16.h>

// Problem constants
#define B_    16
#define T_    1000
#define FEAT  771
#define FEATP 776      // 771 padded to multiple of 8 (16B-aligned fp16 rows)
#define H_    512
#define H3    1536
#define KN_   9
#define KHID  4608     // H*KN
#define M_    16000    // B*T
#define NOUT  257      // output column slice [257:514)

typedef _Float16 half8 __attribute__((ext_vector_type(8)));
typedef _Float16 half4 __attribute__((ext_vector_type(4)));
typedef _Float16 half2v __attribute__((ext_vector_type(2)));
typedef float    floatx4 __attribute__((ext_vector_type(4)));

__device__ inline half8 h8zero() {
    half8 v;
    #pragma unroll
    for (int i = 0; i < 8; ++i) v[i] = (_Float16)0.f;
    return v;
}

// tanh(z) = 1 - 2/(1+e^{2z})  — saturates correctly at +/-inf, no NaN
__device__ inline float tanh_fast(float z) {
    return 1.0f - 2.0f / (1.0f + __expf(2.0f * z));
}
__device__ inline float sigmoid_fast(float z) {
    return 1.0f / (1.0f + __expf(-z));
}

// ---------------------------------------------------------------------------
// fp32 -> fp16 convert of inputs, padding rows 771 -> 776 with zeros
__global__ void convert_inputs(const float* __restrict__ in, _Float16* __restrict__ A1) {
    size_t i = (size_t)blockIdx.x * 256 + threadIdx.x;
    if (i >= (size_t)M_ * FEATP) return;
    size_t r = i / FEATP;
    int   cc = (int)(i % FEATP);
    A1[i] = (cc < FEAT) ? (_Float16)in[r * FEAT + cc] : (_Float16)0.f;
}

// ---------------------------------------------------------------------------
// LDS-tiled transpose+convert: Wt[n*Kp + k] = (k<K) ? W[k*ldw + coloff + n] : 0
__global__ __launch_bounds__(256) void transpose_w(
    const float* __restrict__ W, _Float16* __restrict__ Wt,
    int K, int N, int ldw, int coloff, int Kp)
{
    __shared__ float tile[32][33];
    const int kb = blockIdx.x * 32;
    const int nb = blockIdx.y * 32;
    const int tx = threadIdx.x & 31;
    const int ty = threadIdx.x >> 5;   // 0..7
    #pragma unroll
    for (int r = ty; r < 32; r += 8) {
        const int k = kb + r, n = nb + tx;
        tile[r][tx] = (k < K && n < N) ? W[(size_t)k * ldw + coloff + n] : 0.f;
    }
    __syncthreads();
    #pragma unroll
    for (int r = ty; r < 32; r += 8) {
        const int n = nb + r, k = kb + tx;
        if (n < N && k < Kp) Wt[(size_t)n * Kp + k] = (_Float16)tile[tx][r];
    }
}

// ---------------------------------------------------------------------------
// Tiled fp16 MFMA GEMM: C[M x N] = A[M x Kp] * Bt[N x Kp]^T, fp32 accumulate.
// 128x128 block tile, BK=32, 4 waves (2x2), each wave 4x4 of 16x16x32 MFMA.
// EPI 0: tanh(+bias) -> dense fp16 Ch[row*ldc+col] AND packed slot3 Ch2[row*2048+col*4+3]
// EPI 1: raw -> packed Ch[row*2048 + (col&511)*4 + (col>>9)]  (SRU U layout)
// EPI 2: sigmoid(+bias)*aux -> fp32 out
template <int EPI>
__global__ __launch_bounds__(256) void gemm_kernel(
    const _Float16* __restrict__ A, const _Float16* __restrict__ Bt,
    int Kp, int nk, int Nb,
    _Float16* __restrict__ Ch, _Float16* __restrict__ Ch2,
    float* __restrict__ Cf, int ldc,
    const float* __restrict__ bias, const float* __restrict__ aux)
{
    __shared__ __align__(16) _Float16 As[128][40];  // +8 pad, 16B-aligned rows
    __shared__ __align__(16) _Float16 Bs[128][40];

    const int tid  = threadIdx.x;
    const int m0   = blockIdx.x * 128;
    const int n0   = blockIdx.y * 128;
    const int wave = tid >> 6;
    const int lane = tid & 63;
    const int wr   = (wave >> 1) << 6;   // wave row offset (0/64)
    const int wc   = (wave & 1) << 6;    // wave col offset (0/64)
    const int lrow = lane & 15;
    const int lq   = lane >> 4;          // 0..3
    const int srow = tid >> 1;           // staging row 0..127
    const int scol = (tid & 1) << 4;     // staging col 0 or 16

    floatx4 acc[4][4];
    #pragma unroll
    for (int i = 0; i < 4; ++i)
        #pragma unroll
        for (int j = 0; j < 4; ++j)
            #pragma unroll
            for (int r = 0; r < 4; ++r) acc[i][j][r] = 0.f;

    const _Float16* aRow = A + (size_t)(m0 + srow) * Kp;
    const int  brow   = n0 + srow;
    const _Float16* bRow = Bt + (size_t)brow * Kp;
    const bool bvalid = (brow < Nb);

    for (int kc = 0; kc < nk; ++kc) {
        const int k0 = kc << 5;
        __syncthreads();
        #pragma unroll
        for (int s = 0; s < 2; ++s) {
            const int kk = k0 + scol + s * 8;
            half8 va = h8zero(), vb = h8zero();
            const bool kin = (kk + 8 <= Kp);
            if (kin)           va = *(const half8*)(aRow + kk);
            if (kin && bvalid) vb = *(const half8*)(bRow + kk);
            *(half8*)(&As[srow][scol + s * 8]) = va;
            *(half8*)(&Bs[srow][scol + s * 8]) = vb;
        }
        __syncthreads();

        half8 af[4], bfr[4];
        #pragma unroll
        for (int i = 0; i < 4; ++i) af[i]  = *(const half8*)(&As[wr + i * 16 + lrow][lq * 8]);
        #pragma unroll
        for (int j = 0; j < 4; ++j) bfr[j] = *(const half8*)(&Bs[wc + j * 16 + lrow][lq * 8]);
        #pragma unroll
        for (int i = 0; i < 4; ++i)
            #pragma unroll
            for (int j = 0; j < 4; ++j)
                acc[i][j] = __builtin_amdgcn_mfma_f32_16x16x32_f16(af[i], bfr[j], acc[i][j], 0, 0, 0);
    }

    // Epilogue: C/D layout col=lane&15, row=quad*4+reg
    #pragma unroll
    for (int j = 0; j < 4; ++j) {
        const int col = n0 + wc + j * 16 + lrow;
        if (col >= Nb) continue;
        #pragma unroll
        for (int i = 0; i < 4; ++i) {
            #pragma unroll
            for (int r = 0; r < 4; ++r) {
                const int row = m0 + wr + i * 16 + lq * 4 + r;
                float v = acc[i][j][r];
                if constexpr (EPI == 0) {
                    float z = v + bias[col];
                    const _Float16 hv = (_Float16)tanh_fast(z);
                    Ch[(size_t)row * ldc + col] = hv;
                    Ch2[(size_t)row * 2048 + (col << 2) + 3] = hv;
                } else if constexpr (EPI == 1) {
                    Ch[(size_t)row * 2048 + ((col & 511) << 2) + (col >> 9)] = (_Float16)v;
                } else {
                    float z = v + bias[col];
                    Cf[(size_t)row * NOUT + col] = sigmoid_fast(z) * aux[(size_t)row * FEAT + 257 + col];
                }
            }
        }
    }
}

// ---------------------------------------------------------------------------
// SRU scan over packed U: Upk[m][h][4] = {xt, fp, rp, x} as fp16.
// One coalesced 8B load per step per lane; depth-20 register ring (unrolled,
// compile-time indices -> stays in VGPRs) keeps 20 loads in flight to cover
// HBM latency. 1000 = 50 * 20, no tail.
// Writes dense Xout; if HAS3, also writes slot3 of the NEXT layer's Upk.
template <bool HAS3>
__global__ __launch_bounds__(64) void sru_scan(
    const _Float16* __restrict__ Upk, _Float16* __restrict__ Xout,
    _Float16* __restrict__ Pk3, const float* __restrict__ v, const float* __restrict__ bg)
{
    const int gid = blockIdx.x * 64 + threadIdx.x;
    const int b = gid >> 9;
    const int h = gid & 511;
    const float vf = v[h],      vr = v[512 + h];
    const float bf = bg[h],     br = bg[512 + h];

    const _Float16* p = Upk + ((size_t)b * T_ * 512 + h) * 4;
    _Float16* ox = Xout + (size_t)b * T_ * H_ + h;
    _Float16* o3 = HAS3 ? (Pk3 + ((size_t)b * T_ * 512 + h) * 4 + 3) : nullptr;

    half4 buf[20];
    #pragma unroll
    for (int j = 0; j < 20; ++j) buf[j] = *(const half4*)(p + (size_t)j * 2048);

    float c = 0.f;
    for (int t0 = 0; t0 < T_; t0 += 20) {
        #pragma unroll
        for (int j = 0; j < 20; ++j) {
            const int t = t0 + j;
            const half4 cur = buf[j];
            const int tn = t + 20;
            if (tn < T_) buf[j] = *(const half4*)(p + (size_t)tn * 2048);
            const float xt = (float)cur[0];
            const float fp = (float)cur[1];
            const float rp = (float)cur[2];
            const float x  = (float)cur[3];
            const float f  = sigmoid_fast(fp + vf * c + bf);
            const float r  = sigmoid_fast(rp + vr * c + br);
            const float cn = f * c + (1.0f - f) * xt;
            const float hO = r * cn + (1.0f - r) * x;
            const _Float16 hh = (_Float16)hO;
            ox[(size_t)t * H_] = hh;
            if constexpr (HAS3) o3[(size_t)t * 2048] = hh;
            c = cn;
        }
    }
}

// ---------------------------------------------------------------------------
// Fused conv6x6(asym pad 3,2) + bias + tanh + maxpool3x3(pad 1).
// Weights are read with wave-uniform indices directly from global -> scalar
// loads into SGPRs (zero LDS weight traffic). cv kept in fp16 to halve LDS.
// Row loop rolled to bound register pressure (no scratch).
template <int JJ>
__device__ inline floatx4 window4(floatx4 a, floatx4 b, float r8) {
    floatx4 w;
    if constexpr (JJ == 0)      { w = a; }
    else if constexpr (JJ == 1) { w[0] = a[1]; w[1] = a[2]; w[2] = a[3]; w[3] = b[0]; }
    else if constexpr (JJ == 2) { w[0] = a[2]; w[1] = a[3]; w[2] = b[0]; w[3] = b[1]; }
    else if constexpr (JJ == 3) { w[0] = a[3]; w[1] = b[0]; w[2] = b[1]; w[3] = b[2]; }
    else if constexpr (JJ == 4) { w = b; }
    else                        { w[0] = b[1]; w[1] = b[2]; w[2] = b[3]; w[3] = r8; }
    return w;
}

#define CVW 76   // cv row width (halves)

__global__ __launch_bounds__(320) void conv_pool(
    const _Float16* __restrict__ X, const float* __restrict__ ck,
    const float* __restrict__ cb, _Float16* __restrict__ A3)
{
    __shared__ __align__(16) float    in_s[23][76];       // t0-4..t0+18, h0-4..h0+71 (fp32)
    __shared__ __align__(16) _Float16 cv[9][18][CVW];     // tanh(conv) fp16; -65504 = outside
    const int tid = threadIdx.x;
    int bi = blockIdx.x;
    const int th = bi & 7;  bi >>= 3;
    const int tt = bi % 63;
    const int b  = bi / 63;
    const int t0 = tt * 16, h0 = th * 64;

    for (int i = tid; i < 23 * 76; i += 320) {
        const int r = i / 76, cc = i % 76;
        const int gt = t0 - 4 + r, gh = h0 - 4 + cc;
        float val = 0.f;   // conv zero-padding
        if (gt >= 0 && gt < T_ && gh >= 0 && gh < H_)
            val = (float)X[((size_t)b * T_ + gt) * H_ + gh];
        in_s[r][cc] = val;
    }
    __syncthreads();

    // conv phase: 18 pt x 17 ph-groups = 306 tasks, one per thread
    if (tid < 306) {
        const int pt = tid / 17;        // conv row: ct = t0 - 1 + pt
        const int co = (tid % 17) * 4;  // conv col offset: ch = h0 - 1 + co + q
        const float* inb = &in_s[pt][co];

        const int ct = t0 - 1 + pt;
        const bool rok = (ct >= 0) && (ct < T_);
        const int chb = h0 - 1 + co;
        const bool ok0 = rok && (chb + 0 >= 0) && (chb + 0 < H_);
        const bool ok1 = rok && (chb + 1 >= 0) && (chb + 1 < H_);
        const bool ok2 = rok && (chb + 2 >= 0) && (chb + 2 < H_);
        const bool ok3 = rok && (chb + 3 >= 0) && (chb + 3 < H_);

        #define EMIT_K(K, VV)                                                  \
        {                                                                      \
            const floatx4 vz = (VV);                                           \
            const float bk = cb[K];                                            \
            half4 o;                                                           \
            o[0] = ok0 ? (_Float16)tanh_fast(vz[0] + bk) : (_Float16)(-65504.f); \
            o[1] = ok1 ? (_Float16)tanh_fast(vz[1] + bk) : (_Float16)(-65504.f); \
            o[2] = ok2 ? (_Float16)tanh_fast(vz[2] + bk) : (_Float16)(-65504.f); \
            o[3] = ok3 ? (_Float16)tanh_fast(vz[3] + bk) : (_Float16)(-65504.f); \
            *(half4*)(&cv[K][pt][co]) = o;                                     \
        }

        {   // pass 0: kernels 0..4 (weights via uniform scalar loads)
            floatx4 c0 = 0.f, c1 = 0.f, c2 = 0.f, c3 = 0.f, c4 = 0.f;
            #pragma unroll 1
            for (int ii = 0; ii < 6; ++ii) {
                const float* row = inb + ii * 76;
                const floatx4 ra = *(const floatx4*)(row);
                const floatx4 rb = *(const floatx4*)(row + 4);
                const float   r8 = row[8];
                const float* wt = ck + ii * 6;   // + k*36 + jj, wave-uniform
                #define TAP0(J)                                                \
                {                                                              \
                    const floatx4 win = window4<J>(ra, rb, r8);                \
                    c0 += wt[0 * 36 + (J)] * win;                              \
                    c1 += wt[1 * 36 + (J)] * win;                              \
                    c2 += wt[2 * 36 + (J)] * win;                              \
                    c3 += wt[3 * 36 + (J)] * win;                              \
                    c4 += wt[4 * 36 + (J)] * win;                              \
                }
                TAP0(0) TAP0(1) TAP0(2) TAP0(3) TAP0(4) TAP0(5)
                #undef TAP0
            }
            EMIT_K(0, c0) EMIT_K(1, c1) EMIT_K(2, c2) EMIT_K(3, c3) EMIT_K(4, c4)
        }
        {   // pass 1: kernels 5..8
            floatx4 c0 = 0.f, c1 = 0.f, c2 = 0.f, c3 = 0.f;
            #pragma unroll 1
            for (int ii = 0; ii < 6; ++ii) {
                const float* row = inb + ii * 76;
                const floatx4 ra = *(const floatx4*)(row);
                const floatx4 rb = *(const floatx4*)(row + 4);
                const float   r8 = row[8];
                const float* wt = ck + 5 * 36 + ii * 6;
                #define TAP1(J)                                                \
                {                                                              \
                    const floatx4 win = window4<J>(ra, rb, r8);                \
                    c0 += wt[0 * 36 + (J)] * win;                              \
                    c1 += wt[1 * 36 + (J)] * win;                              \
                    c2 += wt[2 * 36 + (J)] * win;                              \
                    c3 += wt[3 * 36 + (J)] * win;                              \
                }
                TAP1(0) TAP1(1) TAP1(2) TAP1(3) TAP1(4) TAP1(5)
                #undef TAP1
            }
            EMIT_K(5, c0) EMIT_K(6, c1) EMIT_K(7, c2) EMIT_K(8, c3)
        }
        #undef EMIT_K
    }
    __syncthreads();

    // pool phase: 16 pt x 16 ph-groups of 4 = 256 tasks
    if (tid < 256) {
        const int pt = tid >> 4;
        const int gt = t0 + pt;
        if (gt < T_) {
            const int ph = (tid & 15) * 4;
            _Float16* dst = A3 + ((size_t)b * T_ + gt) * KHID + (size_t)(h0 + ph) * KN_;
            #pragma unroll
            for (int k = 0; k < 9; ++k) {
                float q0 = -1e30f, q1 = -1e30f, q2 = -1e30f, q3 = -1e30f;
                #pragma unroll
                for (int dr = 0; dr < 3; ++dr) {
                    const _Float16* cr = &cv[k][pt + dr][ph];
                    const half4  a = *(const half4*)(cr);
                    const half2v bq = *(const half2v*)(cr + 4);
                    const float v0 = (float)a[0], v1 = (float)a[1], v2 = (float)a[2];
                    const float v3 = (float)a[3], v4 = (float)bq[0], v5 = (float)bq[1];
                    const float t01 = fmaxf(v1, v2);
                    const float t34 = fmaxf(v3, v4);
                    q0 = fmaxf(q0, fmaxf(v0, t01));
                    q1 = fmaxf(q1, fmaxf(t01, v3));
                    q2 = fmaxf(q2, fmaxf(v2, t34));
                    q3 = fmaxf(q3, fmaxf(t34, v5));
                }
                dst[0 * KN_ + k] = (_Float16)q0;
                dst[1 * KN_ + k] = (_Float16)q1;
                dst[2 * KN_ + k] = (_Float16)q2;
                dst[3 * KN_ + k] = (_Float16)q3;
            }
        }
    }
}

// ---------------------------------------------------------------------------
extern "C" void kernel_launch(void* const* d_in, const int* in_sizes, int n_in,
                              void* d_out, int out_size, void* d_ws, size_t ws_size,
                              hipStream_t stream) {
    const float* inputs = (const float*)d_in[0];
    const float* W_in   = (const float*)d_in[1];
    const float* b_in   = (const float*)d_in[2];
    const float* W_rnn  = (const float*)d_in[3];
    const float* v_rnn  = (const float*)d_in[4];
    const float* b_rnn  = (const float*)d_in[5];
    const float* conv_k = (const float*)d_in[6];
    const float* conv_b = (const float*)d_in[7];
    const float* W_out  = (const float*)d_in[8];
    const float* b_out  = (const float*)d_in[9];
    float* out = (float*)d_out;

    char* ws = (char*)d_ws;
    size_t off = 0;
    auto take = [&](size_t bytes) -> char* {
        off = (off + 255) & ~(size_t)255;
        char* p = ws + off;
        off += bytes;
        return p;
    };
    _Float16* A1   = (_Float16*)take((size_t)M_ * FEATP * 2);   // inputs fp16, padded
    _Float16* W1T  = (_Float16*)take((size_t)H_ * FEATP * 2);   // W_in^T
    _Float16* W2T0 = (_Float16*)take((size_t)H3 * H_ * 2);      // W_rnn[0]^T
    _Float16* W2T1 = (_Float16*)take((size_t)H3 * H_ * 2);      // W_rnn[1]^T
    _Float16* W3T  = (_Float16*)take((size_t)NOUT * KHID * 2);  // W_out[:,257:514]^T
    _Float16* X0   = (_Float16*)take((size_t)M_ * H_ * 2);
    _Float16* X1   = (_Float16*)take((size_t)M_ * H_ * 2);
    _Float16* A3   = (_Float16*)take((size_t)M_ * KHID * 2);    // pooled conv, (h*9+k) layout
    // Upk0/Upk1 alias the A3 region (dead before conv_pool writes A3):
    _Float16* Upk0 = A3;                                        // [M][512][4] packed U, layer 0
    _Float16* Upk1 = A3 + (size_t)M_ * 2048;                    // layer 1
    _Float16* X2   = X0;  // X0 dead after layer-0 GEMM -> reuse

    // --- weight/input preprocessing (fp32 -> fp16, transpose to NxK) ---
    {
        size_t n = (size_t)M_ * FEATP;
        convert_inputs<<<dim3((unsigned)((n + 255) / 256)), 256, 0, stream>>>(inputs, A1);
    }
    transpose_w<<<dim3(25, 16), 256, 0, stream>>>(W_in, W1T, FEAT, H_, H_, 0, FEATP);
    transpose_w<<<dim3(16, 48), 256, 0, stream>>>(W_rnn, W2T0, H_, H3, H3, 0, H_);
    transpose_w<<<dim3(16, 48), 256, 0, stream>>>(W_rnn + (size_t)H_ * H3, W2T1, H_, H3, H3, 0, H_);
    transpose_w<<<dim3(144, 9), 256, 0, stream>>>(W_out, W3T, KHID, NOUT, FEAT, 257, KHID);

    // --- G1: X0 = tanh(inputs @ W_in + b_in); also writes slot3 of Upk0 ---
    gemm_kernel<0><<<dim3(125, 4), 256, 0, stream>>>(A1, W1T, FEATP, 25, H_, X0, Upk0, nullptr, H_, b_in, nullptr);

    // --- SRU layer 0 ---
    gemm_kernel<1><<<dim3(125, 12), 256, 0, stream>>>(X0, W2T0, H_, 16, H3, Upk0, nullptr, nullptr, 0, nullptr, nullptr);
    sru_scan<true><<<dim3(128), 64, 0, stream>>>(Upk0, X1, Upk1, v_rnn, b_rnn);

    // --- SRU layer 1 ---
    gemm_kernel<1><<<dim3(125, 12), 256, 0, stream>>>(X1, W2T1, H_, 16, H3, Upk1, nullptr, nullptr, 0, nullptr, nullptr);
    sru_scan<false><<<dim3(128), 64, 0, stream>>>(Upk1, X2, nullptr, v_rnn + 1024, b_rnn + 1024);

    // --- conv + tanh + maxpool fused, producing final-GEMM A matrix ---
    conv_pool<<<dim3(16 * 63 * 8), 320, 0, stream>>>(X2, conv_k, conv_b, A3);

    // --- G3: out = sigmoid(A3 @ W_out[:,257:514] + b_out[257:514]) * inputs[:,:,257:514] ---
    gemm_kernel<2><<<dim3(125, 3), 256, 0, stream>>>(A3, W3T, KHID, 144, NOUT, nullptr, nullptr, out, NOUT, b_out + 257, inputs);
}